// Round 7
// baseline (136.827 us; speedup 1.0000x reference)
//
#include <hip/hip_runtime.h>
#include <cmath>
#include <cstdint>

#define NW      14
#define NST     (1 << NW)       // 16384 amplitudes
#define THREADS 1024
#define NPASS   12              // layers 1..3 x 4 groups
#define WTP     512             // per-pass W table: TR[256] + TI[256] f16

typedef _Float16 f16;
typedef __fp16   fp16x2 __attribute__((ext_vector_type(2)));   // cvt_pkrtz native type
typedef _Float16 f16x8 __attribute__((ext_vector_type(8)));
typedef float    f32x4 __attribute__((ext_vector_type(4)));
typedef unsigned short u16;

// Per-pass XOR-mask addressing: storage = sigma(phi_p(x)) (GF(2) bijection).
// sigma (bank-balancing linear swizzle) is folded into the masks host-side.
struct PassArg { u16 Mm[4]; u16 Mt[2]; u16 Mw[4]; };
struct Plan { PassArg ps[NPASS]; u16 initM[14]; u16 measR; u16 _pad; };

__device__ __forceinline__ float2 cmulf(float2 a, float2 b) {
    return make_float2(a.x * b.x - a.y * b.y, a.x * b.y + a.y * b.x);
}

__global__ __launch_bounds__(THREADS)
void vqc_kernel(const float* __restrict__ x_raw, const float* __restrict__ angles,
                float* __restrict__ out, Plan pl)
{
    extern __shared__ char smem[];
    f16*    Sh  = (f16*)smem;                    // buf0: Re [0,16K), Im [16K,32K); buf1: [32K,64K)
    f16*    Wt  = Sh + 4 * NST;                  // NPASS*512: TR then TI per pass
    float2* G   = (float2*)(Wt + NPASS * WTP);   // 4*14 fused 2x2 gates
    float*  red = (float*)(G + 4 * NW * 4);

    const int b   = blockIdx.x;
    const int tid = threadIdx.x;
    const int lane = tid & 63, wv = tid >> 6;
    const int q = lane >> 4, m = lane & 15;

    // ---- fused per-wire gates: U = RZ(c)*RY(b)*RX(a) [layer0: *RY_enc(x)] ----
    if (tid < 4 * NW) {
        const int k = tid / NW, w = tid % NW;
        const float a  = angles[(k * NW + w) * 3 + 0];
        const float bb = angles[(k * NW + w) * 3 + 1];
        const float c  = angles[(k * NW + w) * 3 + 2];
        float sa, ca, sb, cb, sc, cc;
        sincosf(a * 0.5f, &sa, &ca);
        sincosf(bb * 0.5f, &sb, &cb);
        sincosf(c * 0.5f, &sc, &cc);
        float2 m00 = make_float2(cb * ca,  sb * sa);
        float2 m01 = make_float2(-sb * ca, -cb * sa);
        float2 m10 = make_float2(sb * ca,  -cb * sa);
        float2 m11 = make_float2(cb * ca,  -sb * sa);
        const float2 e0 = make_float2(cc, -sc), e1 = make_float2(cc, sc);
        float2 u00 = cmulf(e0, m00), u01 = cmulf(e0, m01);
        float2 u10 = cmulf(e1, m10), u11 = cmulf(e1, m11);
        if (k == 0) {
            const float xe = tanhf(x_raw[b * NW + w]) * 3.14159265358979f;
            float se, ce;
            sincosf(xe * 0.5f, &se, &ce);
            float2 v00 = make_float2(u00.x * ce + u01.x * se, u00.y * ce + u01.y * se);
            float2 v01 = make_float2(-u00.x * se + u01.x * ce, -u00.y * se + u01.y * ce);
            float2 v10 = make_float2(u10.x * ce + u11.x * se, u10.y * ce + u11.y * se);
            float2 v11 = make_float2(-u10.x * se + u11.x * ce, -u10.y * se + u11.y * ce);
            u00 = v00; u01 = v01; u10 = v10; u11 = v11;
        }
        const int gi = (k * NW + w) * 4;
        G[gi + 0] = u00; G[gi + 1] = u01; G[gi + 2] = u10; G[gi + 3] = u11;
    }
    __syncthreads();

    // ---- W tables: TR[a'][a] = Re W[a'][a], TI = Im (16x16 per pass) ----
    // thread l6: a' = l6&15, ahalf = (l6>>4)&1 (a-bit3), dup = l6>>5 (0=TR,1=TI).
    // One contiguous b128 write per thread; bank-quad = {a'1,a'0,ahalf} -> floor.
    if (tid < NPASS * 64) {
        const int p = tid >> 6, l6 = tid & 63;
        const int ap = l6 & 15, ahalf = (l6 >> 4) & 1, dup = l6 >> 5;
        const int layer = (p >> 2) + 1, g = p & 3;

        // factor 3 (acts on a-bit 3): row = ap bit3, col = ahalf
        float2 p3;
        if (g == 3) {
            p3 = make_float2((((ap >> 3) & 1) == ahalf) ? 1.f : 0.f, 0.f);
        } else {
            const int wire = 13 - (10 - 4 * g + 3);
            p3 = G[(layer * NW + wire) * 4 + ((ap >> 3) & 1) * 2 + ahalf];
        }
        // factors 0..2: row fixed by ap, both columns preloaded
        float2 e0a, e0b, e1a, e1b, e2a, e2b;
        {
            const int r0 = ap & 1, r1 = (ap >> 1) & 1, r2 = (ap >> 2) & 1;
            if (g == 3) {
                const float2* G13 = G + (layer * NW + 13) * 4;   // factor 0
                const float2* G12 = G + (layer * NW + 12) * 4;   // factor 1
                e0a = G13[r0 * 2 + 0]; e0b = G13[r0 * 2 + 1];
                e1a = G12[r1 * 2 + 0]; e1b = G12[r1 * 2 + 1];
                e2a = make_float2(r2 == 0 ? 1.f : 0.f, 0.f);     // identity pad
                e2b = make_float2(r2 == 1 ? 1.f : 0.f, 0.f);
            } else {
                const float2* G0 = G + (layer * NW + (13 - (10 - 4 * g + 0))) * 4;
                const float2* G1 = G + (layer * NW + (13 - (10 - 4 * g + 1))) * 4;
                const float2* G2 = G + (layer * NW + (13 - (10 - 4 * g + 2))) * 4;
                e0a = G0[r0 * 2 + 0]; e0b = G0[r0 * 2 + 1];
                e1a = G1[r1 * 2 + 0]; e1b = G1[r1 * 2 + 1];
                e2a = G2[r2 * 2 + 0]; e2b = G2[r2 * 2 + 1];
            }
        }
        f16x8 frag;
        #pragma unroll
        for (int j2 = 0; j2 < 8; ++j2) {
            float2 v = cmulf(p3, (j2 & 4) ? e2b : e2a);
            v = cmulf(v, (j2 & 2) ? e1b : e1a);
            v = cmulf(v, (j2 & 1) ? e0b : e0a);
            frag[j2] = (f16)(dup ? v.y : v.x);
        }
        *(f16x8*)(Wt + p * WTP + dup * 256 + ap * 16 + ahalf * 8) = frag;
    }

    // ---- init: product state after all layer-0 1q gates, placed via initM (buf0) ----
    {
        float2 common = make_float2(1.f, 0.f);
        #pragma unroll
        for (int bit = 0; bit < 10; ++bit) {
            const int w = 13 - bit;
            const float2 f = ((tid >> bit) & 1) ? G[w * 4 + 2] : G[w * 4 + 0];
            common = cmulf(common, f);
        }
        unsigned p10 = 0;
        #pragma unroll
        for (int bit = 0; bit < 10; ++bit)
            p10 ^= ((tid >> bit) & 1) ? (unsigned)pl.initM[bit] : 0u;
        float2 f0[2], f1[2], f2[2], f3[2];
        f0[0] = G[0*4+0]; f0[1] = G[0*4+2];
        f1[0] = G[1*4+0]; f1[1] = G[1*4+2];
        f2[0] = G[2*4+0]; f2[1] = G[2*4+2];
        f3[0] = G[3*4+0]; f3[1] = G[3*4+2];
        #pragma unroll
        for (int j = 0; j < 16; ++j) {
            const float2 o = cmulf(cmulf(f0[(j >> 3) & 1], f1[(j >> 2) & 1]),
                                   cmulf(f2[(j >> 1) & 1], f3[j & 1]));
            const float2 amp = cmulf(common, o);
            const unsigned ph = p10
                ^ ((j & 1) ? pl.initM[10] : 0) ^ ((j & 2) ? pl.initM[11] : 0)
                ^ ((j & 4) ? pl.initM[12] : 0) ^ ((j & 8) ? pl.initM[13] : 0);
            Sh[ph]       = (f16)amp.x;
            Sh[ph + NST] = (f16)amp.y;
        }
    }
    __syncthreads();

    // ---- 12 MFMA passes, ping-pong buffers, one barrier per pass ----
    const unsigned plane_off = (unsigned)(q >> 1) << 14;
    const f32x4 z4 = {0.f, 0.f, 0.f, 0.f};
    #pragma unroll
    for (int p = 0; p < NPASS; ++p) {
        const f16* S = Sh + ((p & 1) ? 2 * NST : 0);
        f16*       D = Sh + ((p & 1) ? 0 : 2 * NST);
        const PassArg& P = pl.ps[p];
        const unsigned pm = ((m & 1) ? P.Mm[0] : 0) ^ ((m & 2) ? P.Mm[1] : 0)
                          ^ ((m & 4) ? P.Mm[2] : 0) ^ ((m & 8) ? P.Mm[3] : 0);
        const unsigned wb = ((wv & 1) ? P.Mw[0] : 0) ^ ((wv & 2) ? P.Mw[1] : 0)
                          ^ ((wv & 4) ? P.Mw[2] : 0) ^ ((wv & 8) ? P.Mw[3] : 0);
        const unsigned b0 = pm ^ wb;
        // W fragments from TR/TI tables (bank-floor reads by construction)
        const f16x8 tr = *(const f16x8*)(Wt + p * WTP +       m * 16 + (q & 1) * 8);
        const f16x8 ti = *(const f16x8*)(Wt + p * WTP + 256 + m * 16 + (q & 1) * 8);
        const f16x8 bf1 = (q < 2) ? tr : -ti;   // [Wr' ; -Wi']
        const f16x8 bf2 = (q < 2) ? ti : tr;    // [Wi' ;  Wr']
        #pragma unroll
        for (int tt = 0; tt < 4; ++tt) {
            const unsigned s0 = b0 ^ ((tt & 1) ? P.Mt[0] : 0) ^ ((tt & 2) ? P.Mt[1] : 0);
            const f16x8 av = *(const f16x8*)(S + plane_off + (s0 ^ ((unsigned)(q & 1) << 3)));
            const f32x4 d1 = __builtin_amdgcn_mfma_f32_16x16x32_f16(av, bf1, z4, 0, 0, 0);
            const f32x4 d2 = __builtin_amdgcn_mfma_f32_16x16x32_f16(av, bf2, z4, 0, 0, 0);
            union { fp16x2 h2[2]; uint2 u; } c1, c2;
            c1.h2[0] = __builtin_amdgcn_cvt_pkrtz(d1[0], d1[1]);
            c1.h2[1] = __builtin_amdgcn_cvt_pkrtz(d1[2], d1[3]);
            c2.h2[0] = __builtin_amdgcn_cvt_pkrtz(d2[0], d2[1]);
            c2.h2[1] = __builtin_amdgcn_cvt_pkrtz(d2[2], d2[3]);
            const unsigned wu = s0 ^ ((unsigned)q << 2);
            *(uint2*)(D + wu)       = c1.u;   // Re plane, b64
            *(uint2*)(D + NST + wu) = c2.u;   // Im plane, b64
        }
        __syncthreads();
    }

    // ---- <Z_0>: sign = parity(s & measR) over storage index s (state in buf0) ----
    float acc = 0.f;
    {
        const unsigned base = (unsigned)tid * 16;
        const f16x8 r0 = *(const f16x8*)(Sh + base);
        const f16x8 r1 = *(const f16x8*)(Sh + (base ^ 8u));
        const f16x8 i0 = *(const f16x8*)(Sh + NST + base);
        const f16x8 i1 = *(const f16x8*)(Sh + NST + (base ^ 8u));
        const int pb = __popc(base & (unsigned)pl.measR) & 1;
        #pragma unroll
        for (int e = 0; e < 8; ++e) {
            float re = (float)r0[e], im = (float)i0[e];
            float pw = fmaf(re, re, im * im);
            acc += (pb ^ (__popc((unsigned)e & (unsigned)pl.measR) & 1)) ? -pw : pw;
            re = (float)r1[e]; im = (float)i1[e];
            pw = fmaf(re, re, im * im);
            acc += (pb ^ (__popc((unsigned)(e + 8) & (unsigned)pl.measR) & 1)) ? -pw : pw;
        }
    }
    #pragma unroll
    for (int off = 32; off > 0; off >>= 1) acc += __shfl_down(acc, off);
    if ((tid & 63) == 0) red[tid >> 6] = acc;
    __syncthreads();
    if (tid == 0) {
        float s = 0.f;
        #pragma unroll
        for (int i = 0; i < THREADS / 64; ++i) s += red[i];
        out[b] = s;
    }
}

// ---------------- host-side GF(2) layout scheduling ----------------
struct GFm { u16 col[14]; };   // col[b] = image of e_b

static unsigned ringp_host(unsigned x) {
    unsigned s = x;
    s ^= s >> 1; s ^= s >> 2; s ^= s >> 4; s ^= s >> 8;
    s &= 0x3FFFu;
    return (s ^ ((s & 1u) << 13)) & 0x3FFFu;
}
static u16 gf_apply(const GFm& m, u16 v) {
    u16 r = 0;
    for (int b = 0; b < 14; ++b) if ((v >> b) & 1) r ^= m.col[b];
    return r;
}
static GFm gf_compose(const GFm& A, const GFm& B) {   // A∘B
    GFm C;
    for (int b = 0; b < 14; ++b) C.col[b] = gf_apply(A, B.col[b]);
    return C;
}
static void rows_from(const GFm& A, u16 r[14]) {
    for (int i = 0; i < 14; ++i) {
        u16 mm = 0;
        for (int b = 0; b < 14; ++b) mm |= (u16)(((A.col[b] >> i) & 1) << b);
        r[i] = mm;
    }
}
static GFm from_rows(const u16 r[14]) {
    GFm A;
    for (int b = 0; b < 14; ++b) {
        u16 c = 0;
        for (int i = 0; i < 14; ++i) c |= (u16)(((r[i] >> b) & 1) << i);
        A.col[b] = c;
    }
    return A;
}
static GFm gf_inv(const GFm& A) {
    u16 M[14], I[14];
    rows_from(A, M);
    for (int i = 0; i < 14; ++i) I[i] = (u16)(1u << i);
    for (int c = 0; c < 14; ++c) {
        int p = c;
        while (p < 14 && !((M[p] >> c) & 1)) ++p;
        if (p == 14) continue;
        u16 t = M[c]; M[c] = M[p]; M[p] = t;
        t = I[c]; I[c] = I[p]; I[p] = t;
        for (int r2 = 0; r2 < 14; ++r2)
            if (r2 != c && ((M[r2] >> c) & 1)) { M[r2] ^= M[c]; I[r2] ^= I[c]; }
    }
    return from_rows(I);
}

static void build_plan(Plan& pl) {
    GFm ring, ringInv;
    for (int b = 0; b < 14; ++b) ring.col[b] = (u16)ringp_host(1u << b);
    ringInv = gf_inv(ring);

    GFm phi;
    for (int j = 0; j < 4; ++j) phi.col[10 + j] = (u16)(1u << j);
    for (int j = 0; j < 4; ++j) phi.col[6 + j]  = (u16)(1u << (4 + j));
    for (int j = 0; j < 4; ++j) phi.col[2 + j]  = (u16)(1u << (8 + j));
    phi.col[0] = (u16)(1u << 12);
    phi.col[1] = (u16)(1u << 13);

    for (int b = 0; b < 14; ++b) pl.initM[b] = gf_apply(phi, ring.col[b]);

    const int gb[4][4] = {{10,11,12,13},{6,7,8,9},{2,3,4,5},{0,1,6,7}};

    for (int p = 0; p < NPASS; ++p) {
        const int g = p & 3;
        u16 uv[4];
        if (g < 3) for (int j = 0; j < 4; ++j) uv[j] = (u16)(1u << gb[g + 1][j]);
        else       for (int j = 0; j < 4; ++j) uv[j] = ringInv.col[10 + j];
        for (int j = 0; j < 4; ++j) pl.ps[p].Mm[j] = gf_apply(phi, uv[j]);

        u16 span[14]; int ns = 0;
        u16 tv[6]; int nt = 0;
        auto tryAdd = [&](u16 v) -> bool {
            bool ch = true;
            while (ch) {
                ch = false;
                for (int i = 0; i < ns; ++i) {
                    const int tb = 31 - __builtin_clz((unsigned)span[i]);
                    if ((v >> tb) & 1) { v ^= span[i]; ch = true; }
                }
            }
            if (!v) return false;
            span[ns++] = v;
            return true;
        };
        for (int j = 0; j < 4; ++j) tryAdd((u16)(1u << gb[g][j]));
        for (int j = 0; j < 4; ++j) tryAdd(uv[j]);
        for (int b2 = 0; b2 < 14 && nt < 6; ++b2)
            if (tryAdd((u16)(1u << b2))) tv[nt++] = (u16)(1u << b2);
        for (int i = 0; i < 2; ++i) pl.ps[p].Mt[i] = gf_apply(phi, tv[i]);
        for (int i = 0; i < 4; ++i) pl.ps[p].Mw[i] = gf_apply(phi, tv[i + 2]);

        GFm Bm;
        for (int j = 0; j < 4; ++j) Bm.col[j]     = (u16)(1u << gb[g][j]);
        for (int j = 0; j < 4; ++j) Bm.col[4 + j] = uv[j];
        for (int i = 0; i < 6; ++i) Bm.col[8 + i] = tv[i];
        GFm Binv = gf_inv(Bm);
        u16 img[14];
        for (int j = 0; j < 4; ++j) img[j]     = pl.ps[p].Mm[j];
        for (int j = 0; j < 4; ++j) img[4 + j] = (u16)(1u << j);
        for (int i = 0; i < 6; ++i) img[8 + i] = gf_apply(phi, tv[i]);
        GFm nphi;
        for (int b2 = 0; b2 < 14; ++b2) {
            const u16 coef = gf_apply(Binv, (u16)(1u << b2));
            u16 v = 0;
            for (int j = 0; j < 14; ++j) if ((coef >> j) & 1) v ^= img[j];
            nphi.col[b2] = v;
        }
        if (g == 3) nphi = gf_compose(nphi, ringInv);
        phi = nphi;
    }

    GFm pinv = gf_inv(phi);
    u16 rows[14];
    rows_from(pinv, rows);
    pl.measR = rows[13];
    pl._pad = 0;
}

// ---- bank-balancing swizzle: sigma(v) = v ^ (par(v&R4)<<4) ^ (par(v&R5)<<5),
// R4,R5 subset bits [13:6].  Involution; folded into all plan masks. ----
static inline int par16(unsigned v) { return __builtin_parity(v); }

static void apply_sigma(Plan& pl) {
    unsigned bestR4 = 0, bestR5 = 0; int bestBad = 1 << 30;
    for (unsigned r4 = 0; r4 < 256 && bestBad > 0; ++r4) {
        for (unsigned r5 = 0; r5 < 256; ++r5) {
            const unsigned R4 = r4 << 6, R5 = r5 << 6;
            int bad = 0;
            for (int p = 0; p < NPASS; ++p) {
                bool seen[4] = {false, false, false, false};
                int distinct = 0;
                for (int j = 0; j < 4; ++j) {
                    const unsigned w = pl.ps[p].Mm[j];
                    const int b4 = ((w >> 4) & 1) ^ par16(w & R4);
                    const int b5 = ((w >> 5) & 1) ^ par16(w & R5);
                    const int v = b4 | (b5 << 1);
                    if (v && !seen[v]) { seen[v] = true; ++distinct; }
                }
                if (distinct < 2) ++bad;   // m->(bit4,bit5) map not surjective
            }
            if (bad < bestBad) { bestBad = bad; bestR4 = R4; bestR5 = R5; }
            if (bestBad == 0) break;
        }
    }
    const unsigned R4 = bestR4, R5 = bestR5;
    auto sig = [&](u16 v) -> u16 {
        return (u16)(v ^ (par16(v & R4) << 4) ^ (par16(v & R5) << 5));
    };
    for (int p = 0; p < NPASS; ++p) {
        for (int j = 0; j < 4; ++j) pl.ps[p].Mm[j] = sig(pl.ps[p].Mm[j]);
        for (int j = 0; j < 2; ++j) pl.ps[p].Mt[j] = sig(pl.ps[p].Mt[j]);
        for (int j = 0; j < 4; ++j) pl.ps[p].Mw[j] = sig(pl.ps[p].Mw[j]);
    }
    for (int b = 0; b < 14; ++b) pl.initM[b] = sig(pl.initM[b]);
    // measR transforms by sigma^T: r ^ (bit4(r)?R4:0) ^ (bit5(r)?R5:0)
    u16 r = pl.measR;
    r ^= ((r >> 4) & 1) ? (u16)R4 : 0;
    r ^= ((r >> 5) & 1) ? (u16)R5 : 0;
    pl.measR = r;
}

extern "C" void kernel_launch(void* const* d_in, const int* in_sizes, int n_in,
                              void* d_out, int out_size, void* d_ws, size_t ws_size,
                              hipStream_t stream) {
    const float* x_raw  = (const float*)d_in[0];
    const float* angles = (const float*)d_in[1];
    float* out = (float*)d_out;
    const int bsz = in_sizes[0] / NW;

    Plan pl;
    build_plan(pl);
    apply_sigma(pl);

    const size_t lds = (size_t)4 * NST * sizeof(f16)          // 2x ping-pong state planes
                     + (size_t)NPASS * WTP * sizeof(f16)      // TR/TI W tables
                     + (size_t)4 * NW * 4 * sizeof(float2)    // fused gates
                     + (size_t)(THREADS / 64) * sizeof(float);
    (void)hipFuncSetAttribute((const void*)vqc_kernel,
                              hipFuncAttributeMaxDynamicSharedMemorySize, (int)lds);
    vqc_kernel<<<dim3(bsz), dim3(THREADS), lds, stream>>>(x_raw, angles, out, pl);
}

// Round 8
// 118.920 us; speedup vs baseline: 1.1506x; 1.1506x over previous
//
#include <hip/hip_runtime.h>
#include <cmath>
#include <cstdint>

#define NW      14
#define NST     (1 << NW)       // 16384 amplitudes
#define THREADS 512
#define NPASS   12              // layers 1..3 x 4 groups
#define WTP     512             // per-pass W table: TR[256] + TI[256] f16

typedef _Float16 f16;
typedef _Float16 f16x8 __attribute__((ext_vector_type(8)));
typedef float    f32x4 __attribute__((ext_vector_type(4)));
typedef unsigned short u16;

// Per-pass XOR-mask addressing: storage = phi_p(x) (GF(2) bijection).
// Mm[j] = phi(u_j) (u_j = next pass's gate generators = in-tile coset dirs,
// also this pass's a'-write placement). Mt (tile, 3 bits) / Mw (wave, 3 bits).
struct PassArg { u16 Mm[4]; u16 Mt[3]; u16 Mw[3]; };
struct Plan { PassArg ps[NPASS]; u16 initM[14]; u16 measR; u16 _pad; };

__device__ __forceinline__ float2 cmulf(float2 a, float2 b) {
    return make_float2(a.x * b.x - a.y * b.y, a.x * b.y + a.y * b.x);
}
// bank-spread hash (rounds 4/5, empirically best): XORs bits [5:3] from high bits
__device__ __forceinline__ unsigned swzu(unsigned s) {
    return s ^ ((((s >> 6) ^ (s >> 9) ^ (s >> 11)) & 7u) << 3);
}
// W-table in-block offset with quad-spread (keeps 8-f16 alignment)
__device__ __forceinline__ unsigned wtofs(unsigned m, unsigned q01) {
    return (m * 16 + q01 * 8) ^ (((m >> 2) & 1u) << 3);
}

__global__ __launch_bounds__(THREADS, 4)
void vqc_kernel(const float* __restrict__ x_raw, const float* __restrict__ angles,
                float* __restrict__ out, Plan pl)
{
    extern __shared__ char smem[];
    f16*    Sh  = (f16*)smem;                    // single buffer: Re [0,16K), Im [16K,32K) f16
    f16*    Wt  = Sh + 2 * NST;                  // NPASS*512: TR then TI per pass
    float2* G   = (float2*)(Wt + NPASS * WTP);   // 4*14 fused 2x2 gates
    float*  red = (float*)G;                     // aliased: G dead after init, red used at end

    const int b   = blockIdx.x;
    const int tid = threadIdx.x;
    const int lane = tid & 63, wv = tid >> 6;    // wv in 0..7
    const int q = lane >> 4, m = lane & 15;

    // ---- fused per-wire gates: U = RZ(c)*RY(b)*RX(a) [layer0: *RY_enc(x)] ----
    if (tid < 4 * NW) {
        const int k = tid / NW, w = tid % NW;
        const float a  = angles[(k * NW + w) * 3 + 0];
        const float bb = angles[(k * NW + w) * 3 + 1];
        const float c  = angles[(k * NW + w) * 3 + 2];
        float sa, ca, sb, cb, sc, cc;
        sincosf(a * 0.5f, &sa, &ca);
        sincosf(bb * 0.5f, &sb, &cb);
        sincosf(c * 0.5f, &sc, &cc);
        float2 m00 = make_float2(cb * ca,  sb * sa);
        float2 m01 = make_float2(-sb * ca, -cb * sa);
        float2 m10 = make_float2(sb * ca,  -cb * sa);
        float2 m11 = make_float2(cb * ca,  -sb * sa);
        const float2 e0 = make_float2(cc, -sc), e1 = make_float2(cc, sc);
        float2 u00 = cmulf(e0, m00), u01 = cmulf(e0, m01);
        float2 u10 = cmulf(e1, m10), u11 = cmulf(e1, m11);
        if (k == 0) {
            const float xe = tanhf(x_raw[b * NW + w]) * 3.14159265358979f;
            float se, ce;
            sincosf(xe * 0.5f, &se, &ce);
            float2 v00 = make_float2(u00.x * ce + u01.x * se, u00.y * ce + u01.y * se);
            float2 v01 = make_float2(-u00.x * se + u01.x * ce, -u00.y * se + u01.y * ce);
            float2 v10 = make_float2(u10.x * ce + u11.x * se, u10.y * ce + u11.y * se);
            float2 v11 = make_float2(-u10.x * se + u11.x * ce, -u10.y * se + u11.y * ce);
            u00 = v00; u01 = v01; u10 = v10; u11 = v11;
        }
        const int gi = (k * NW + w) * 4;
        G[gi + 0] = u00; G[gi + 1] = u01; G[gi + 2] = u10; G[gi + 3] = u11;
    }
    __syncthreads();

    // ---- W tables: TR[a'][a] = Re W[a'][a], TI = Im (16x16 per pass) ----
    // 768 builder slots over 512 threads (2 iterations). RNE casts. No private arrays.
    #pragma unroll
    for (int it = 0; it < 2; ++it) {
        const int t2 = tid + it * THREADS;
        if (t2 < NPASS * 64) {
            const int p = t2 >> 6, l6 = t2 & 63;
            const int ap = l6 & 15, ahalf = (l6 >> 4) & 1, dup = l6 >> 5;
            const int layer = (p >> 2) + 1, g = p & 3;

            float2 p3;
            if (g == 3) {
                p3 = make_float2((((ap >> 3) & 1) == ahalf) ? 1.f : 0.f, 0.f);
            } else {
                const int wire = 13 - (10 - 4 * g + 3);
                p3 = G[(layer * NW + wire) * 4 + ((ap >> 3) & 1) * 2 + ahalf];
            }
            float2 e0a, e0b, e1a, e1b, e2a, e2b;
            {
                const int r0 = ap & 1, r1 = (ap >> 1) & 1, r2 = (ap >> 2) & 1;
                if (g == 3) {
                    const float2* G13 = G + (layer * NW + 13) * 4;
                    const float2* G12 = G + (layer * NW + 12) * 4;
                    e0a = G13[r0 * 2 + 0]; e0b = G13[r0 * 2 + 1];
                    e1a = G12[r1 * 2 + 0]; e1b = G12[r1 * 2 + 1];
                    e2a = make_float2(r2 == 0 ? 1.f : 0.f, 0.f);
                    e2b = make_float2(r2 == 1 ? 1.f : 0.f, 0.f);
                } else {
                    const float2* G0 = G + (layer * NW + (13 - (10 - 4 * g + 0))) * 4;
                    const float2* G1 = G + (layer * NW + (13 - (10 - 4 * g + 1))) * 4;
                    const float2* G2 = G + (layer * NW + (13 - (10 - 4 * g + 2))) * 4;
                    e0a = G0[r0 * 2 + 0]; e0b = G0[r0 * 2 + 1];
                    e1a = G1[r1 * 2 + 0]; e1b = G1[r1 * 2 + 1];
                    e2a = G2[r2 * 2 + 0]; e2b = G2[r2 * 2 + 1];
                }
            }
            f16x8 frag;
            #pragma unroll
            for (int j2 = 0; j2 < 8; ++j2) {
                float2 v = cmulf(p3, (j2 & 4) ? e2b : e2a);
                v = cmulf(v, (j2 & 2) ? e1b : e1a);
                v = cmulf(v, (j2 & 1) ? e0b : e0a);
                frag[j2] = (f16)(dup ? v.y : v.x);
            }
            *(f16x8*)(Wt + p * WTP + dup * 256 + wtofs(ap, ahalf)) = frag;
        }
    }

    // ---- init: product state after all layer-0 1q gates, placed via initM ----
    {
        float2 common = make_float2(1.f, 0.f);
        #pragma unroll
        for (int bit = 0; bit < 9; ++bit) {          // x bits 0..8 from tid
            const int w = 13 - bit;
            const float2 f = ((tid >> bit) & 1) ? G[w * 4 + 2] : G[w * 4 + 0];
            common = cmulf(common, f);
        }
        unsigned p9 = 0;
        #pragma unroll
        for (int bit = 0; bit < 9; ++bit)
            p9 ^= ((tid >> bit) & 1) ? (unsigned)pl.initM[bit] : 0u;
        // x bits 9..13 from j: wires 4,3,2,1,0
        float2 f0[2], f1[2], f2[2], f3[2], f4[2];
        f0[0] = G[4*4+0]; f0[1] = G[4*4+2];
        f1[0] = G[3*4+0]; f1[1] = G[3*4+2];
        f2[0] = G[2*4+0]; f2[1] = G[2*4+2];
        f3[0] = G[1*4+0]; f3[1] = G[1*4+2];
        f4[0] = G[0*4+0]; f4[1] = G[0*4+2];
        #pragma unroll
        for (int j = 0; j < 32; ++j) {
            float2 o = cmulf(cmulf(f0[j & 1], f1[(j >> 1) & 1]),
                             cmulf(f2[(j >> 2) & 1], f3[(j >> 3) & 1]));
            o = cmulf(o, f4[(j >> 4) & 1]);
            const float2 amp = cmulf(common, o);
            const unsigned sj = ((j & 1) ? pl.initM[9] : 0) ^ ((j & 2) ? pl.initM[10] : 0)
                              ^ ((j & 4) ? pl.initM[11] : 0) ^ ((j & 8) ? pl.initM[12] : 0)
                              ^ ((j & 16) ? pl.initM[13] : 0);
            const unsigned ph = swzu(p9 ^ sj);
            Sh[ph]       = (f16)amp.x;
            Sh[ph + NST] = (f16)amp.y;
        }
    }
    __syncthreads();

    // ---- 12 MFMA passes, in-place: read 8 tiles -> barrier -> MFMA+write -> barrier ----
    const unsigned plane_off = (unsigned)(q >> 1) << 14;
    const unsigned q01 = (unsigned)(q & 1);
    const f32x4 z4 = {0.f, 0.f, 0.f, 0.f};
    #pragma unroll
    for (int p = 0; p < NPASS; ++p) {
        const PassArg& P = pl.ps[p];
        const unsigned pm = ((m & 1) ? P.Mm[0] : 0) ^ ((m & 2) ? P.Mm[1] : 0)
                          ^ ((m & 4) ? P.Mm[2] : 0) ^ ((m & 8) ? P.Mm[3] : 0);
        const unsigned wb = ((wv & 1) ? P.Mw[0] : 0) ^ ((wv & 2) ? P.Mw[1] : 0)
                          ^ ((wv & 4) ? P.Mw[2] : 0);
        const unsigned b0 = pm ^ wb;
        const f16x8 tr = *(const f16x8*)(Wt + p * WTP +       wtofs((unsigned)m, q01));
        const f16x8 ti = *(const f16x8*)(Wt + p * WTP + 256 + wtofs((unsigned)m, q01));
        const f16x8 bf1 = (q < 2) ? tr : -ti;   // [Wr' ; -Wi']
        const f16x8 bf2 = (q < 2) ? ti : tr;    // [Wi' ;  Wr']
        unsigned sw[8];
        f16x8 av[8];
        #pragma unroll
        for (int tt = 0; tt < 8; ++tt) {
            const unsigned s0 = b0 ^ ((tt & 1) ? P.Mt[0] : 0)
                                   ^ ((tt & 2) ? P.Mt[1] : 0)
                                   ^ ((tt & 4) ? P.Mt[2] : 0);
            sw[tt] = swzu(s0);
            av[tt] = *(const f16x8*)(Sh + plane_off + (sw[tt] ^ (q01 << 3)));
        }
        __syncthreads();    // all reads complete before any in-place write
        #pragma unroll
        for (int tt = 0; tt < 8; ++tt) {
            const f32x4 d1 = __builtin_amdgcn_mfma_f32_16x16x32_f16(av[tt], bf1, z4, 0, 0, 0);
            const f32x4 d2 = __builtin_amdgcn_mfma_f32_16x16x32_f16(av[tt], bf2, z4, 0, 0, 0);
            union { f16 h[4]; uint2 u; } c1, c2;
            #pragma unroll
            for (int r = 0; r < 4; ++r) { c1.h[r] = (f16)d1[r]; c2.h[r] = (f16)d2[r]; }
            const unsigned wu = sw[tt] ^ ((unsigned)q << 2);
            *(uint2*)(Sh + wu)       = c1.u;   // Re plane, b64
            *(uint2*)(Sh + NST + wu) = c2.u;   // Im plane, b64
        }
        __syncthreads();
    }

    // ---- <Z_0>: sign = parity(s & measR) over storage index s ----
    float acc = 0.f;
    {
        const unsigned base = (unsigned)tid * 32;
        const unsigned swb  = swzu(base);      // swzu(base^e) = swb^e for e<64
        const int pb = __popc(base & (unsigned)pl.measR) & 1;
        #pragma unroll
        for (int cch = 0; cch < 4; ++cch) {
            const unsigned co = (unsigned)cch * 8;
            const f16x8 rr = *(const f16x8*)(Sh + (swb ^ co));
            const f16x8 ii = *(const f16x8*)(Sh + NST + (swb ^ co));
            #pragma unroll
            for (int e = 0; e < 8; ++e) {
                const float re = (float)rr[e], im = (float)ii[e];
                const float pw = fmaf(re, re, im * im);
                const int sgn = pb ^ (__popc((co | (unsigned)e) & (unsigned)pl.measR) & 1);
                acc += sgn ? -pw : pw;
            }
        }
    }
    #pragma unroll
    for (int off = 32; off > 0; off >>= 1) acc += __shfl_down(acc, off);
    if ((tid & 63) == 0) red[wv] = acc;
    __syncthreads();
    if (tid == 0) {
        float s = 0.f;
        #pragma unroll
        for (int i = 0; i < THREADS / 64; ++i) s += red[i];
        out[b] = s;
    }
}

// ---------------- host-side GF(2) layout scheduling ----------------
struct GFm { u16 col[14]; };   // col[b] = image of e_b

static unsigned ringp_host(unsigned x) {
    unsigned s = x;
    s ^= s >> 1; s ^= s >> 2; s ^= s >> 4; s ^= s >> 8;
    s &= 0x3FFFu;
    return (s ^ ((s & 1u) << 13)) & 0x3FFFu;
}
static u16 gf_apply(const GFm& m, u16 v) {
    u16 r = 0;
    for (int b = 0; b < 14; ++b) if ((v >> b) & 1) r ^= m.col[b];
    return r;
}
static GFm gf_compose(const GFm& A, const GFm& B) {   // A∘B
    GFm C;
    for (int b = 0; b < 14; ++b) C.col[b] = gf_apply(A, B.col[b]);
    return C;
}
static void rows_from(const GFm& A, u16 r[14]) {
    for (int i = 0; i < 14; ++i) {
        u16 mm = 0;
        for (int b = 0; b < 14; ++b) mm |= (u16)(((A.col[b] >> i) & 1) << b);
        r[i] = mm;
    }
}
static GFm from_rows(const u16 r[14]) {
    GFm A;
    for (int b = 0; b < 14; ++b) {
        u16 c = 0;
        for (int i = 0; i < 14; ++i) c |= (u16)(((r[i] >> b) & 1) << i);
        A.col[b] = c;
    }
    return A;
}
static GFm gf_inv(const GFm& A) {
    u16 M[14], I[14];
    rows_from(A, M);
    for (int i = 0; i < 14; ++i) I[i] = (u16)(1u << i);
    for (int c = 0; c < 14; ++c) {
        int p = c;
        while (p < 14 && !((M[p] >> c) & 1)) ++p;
        if (p == 14) continue;
        u16 t = M[c]; M[c] = M[p]; M[p] = t;
        t = I[c]; I[c] = I[p]; I[p] = t;
        for (int r2 = 0; r2 < 14; ++r2)
            if (r2 != c && ((M[r2] >> c) & 1)) { M[r2] ^= M[c]; I[r2] ^= I[c]; }
    }
    return from_rows(I);
}

static void build_plan(Plan& pl) {
    GFm ring, ringInv;
    for (int b = 0; b < 14; ++b) ring.col[b] = (u16)ringp_host(1u << b);
    ringInv = gf_inv(ring);

    GFm phi;
    for (int j = 0; j < 4; ++j) phi.col[10 + j] = (u16)(1u << j);
    for (int j = 0; j < 4; ++j) phi.col[6 + j]  = (u16)(1u << (4 + j));
    for (int j = 0; j < 4; ++j) phi.col[2 + j]  = (u16)(1u << (8 + j));
    phi.col[0] = (u16)(1u << 12);
    phi.col[1] = (u16)(1u << 13);

    for (int b = 0; b < 14; ++b) pl.initM[b] = gf_apply(phi, ring.col[b]);

    const int gb[4][4] = {{10,11,12,13},{6,7,8,9},{2,3,4,5},{0,1,6,7}};

    for (int p = 0; p < NPASS; ++p) {
        const int g = p & 3;
        u16 uv[4];
        if (g < 3) for (int j = 0; j < 4; ++j) uv[j] = (u16)(1u << gb[g + 1][j]);
        else       for (int j = 0; j < 4; ++j) uv[j] = ringInv.col[10 + j];
        for (int j = 0; j < 4; ++j) pl.ps[p].Mm[j] = gf_apply(phi, uv[j]);

        u16 span[14]; int ns = 0;
        u16 tv[6]; int nt = 0;
        auto tryAdd = [&](u16 v) -> bool {
            bool ch = true;
            while (ch) {
                ch = false;
                for (int i = 0; i < ns; ++i) {
                    const int tb = 31 - __builtin_clz((unsigned)span[i]);
                    if ((v >> tb) & 1) { v ^= span[i]; ch = true; }
                }
            }
            if (!v) return false;
            span[ns++] = v;
            return true;
        };
        for (int j = 0; j < 4; ++j) tryAdd((u16)(1u << gb[g][j]));
        for (int j = 0; j < 4; ++j) tryAdd(uv[j]);
        for (int b2 = 0; b2 < 14 && nt < 6; ++b2)
            if (tryAdd((u16)(1u << b2))) tv[nt++] = (u16)(1u << b2);
        for (int i = 0; i < 3; ++i) pl.ps[p].Mt[i] = gf_apply(phi, tv[i]);      // tile (tt)
        for (int i = 0; i < 3; ++i) pl.ps[p].Mw[i] = gf_apply(phi, tv[i + 3]);  // wave (wv)

        GFm Bm;
        for (int j = 0; j < 4; ++j) Bm.col[j]     = (u16)(1u << gb[g][j]);
        for (int j = 0; j < 4; ++j) Bm.col[4 + j] = uv[j];
        for (int i = 0; i < 6; ++i) Bm.col[8 + i] = tv[i];
        GFm Binv = gf_inv(Bm);
        u16 img[14];
        for (int j = 0; j < 4; ++j) img[j]     = pl.ps[p].Mm[j];
        for (int j = 0; j < 4; ++j) img[4 + j] = (u16)(1u << j);
        for (int i = 0; i < 6; ++i) img[8 + i] = gf_apply(phi, tv[i]);
        GFm nphi;
        for (int b2 = 0; b2 < 14; ++b2) {
            const u16 coef = gf_apply(Binv, (u16)(1u << b2));
            u16 v = 0;
            for (int j = 0; j < 14; ++j) if ((coef >> j) & 1) v ^= img[j];
            nphi.col[b2] = v;
        }
        if (g == 3) nphi = gf_compose(nphi, ringInv);
        phi = nphi;
    }

    GFm pinv = gf_inv(phi);
    u16 rows[14];
    rows_from(pinv, rows);
    pl.measR = rows[13];
    pl._pad = 0;
}

extern "C" void kernel_launch(void* const* d_in, const int* in_sizes, int n_in,
                              void* d_out, int out_size, void* d_ws, size_t ws_size,
                              hipStream_t stream) {
    const float* x_raw  = (const float*)d_in[0];
    const float* angles = (const float*)d_in[1];
    float* out = (float*)d_out;
    const int bsz = in_sizes[0] / NW;

    Plan pl;
    build_plan(pl);

    // 64K state + 12K W tables + 3.5K gates = ~79.5 KB -> 2 blocks/CU
    const size_t lds = (size_t)2 * NST * sizeof(f16)
                     + (size_t)NPASS * WTP * sizeof(f16)
                     + (size_t)4 * NW * 4 * sizeof(float2);
    (void)hipFuncSetAttribute((const void*)vqc_kernel,
                              hipFuncAttributeMaxDynamicSharedMemorySize, (int)lds);
    vqc_kernel<<<dim3(bsz), dim3(THREADS), lds, stream>>>(x_raw, angles, out, pl);
}

// Round 9
// 111.889 us; speedup vs baseline: 1.2229x; 1.0628x over previous
//
#include <hip/hip_runtime.h>
#include <cmath>
#include <cstdint>

#define NW       14
#define NST      (1 << NW)      // 16384 amplitudes
#define THREADS  512
#define PRETHR   768
#define NPASS    12             // layers 1..3 x 4 groups
#define WTP      512            // per-pass W table: TR[256] + TI[256] f16

typedef _Float16 f16;
typedef _Float16 f16x8 __attribute__((ext_vector_type(8)));
typedef float    f32x4 __attribute__((ext_vector_type(4)));
typedef unsigned short u16;

// Per-pass XOR-mask addressing: storage = swzu(phi_p(x)); the bank-spread hash
// swzu (GF(2)-linear involution) is folded into all masks HOST-side.
struct PassArg { u16 Mm[4]; u16 Mt[3]; u16 Mw[3]; };
struct Plan { PassArg ps[NPASS]; u16 initM[14]; u16 measR; u16 _pad; };

__device__ __forceinline__ float2 cmulf(float2 a, float2 b) {
    return make_float2(a.x * b.x - a.y * b.y, a.x * b.y + a.y * b.x);
}
// W-table in-block offset with quad-spread (keeps 8-f16 alignment)
__device__ __host__ __forceinline__ unsigned wtofs(unsigned m, unsigned q01) {
    return (m * 16 + q01 * 8) ^ (((m >> 2) & 1u) << 3);
}

// ---------------- pre-kernel: shared tables (angles only) -> d_ws ----------------
__global__ __launch_bounds__(PRETHR)
void vqc_pre(const float* __restrict__ angles, f16* __restrict__ wt_g,
             float2* __restrict__ u0_g)
{
    __shared__ float2 G[4 * NW * 4];
    const int tid = threadIdx.x;

    if (tid < 4 * NW) {
        const int k = tid / NW, w = tid % NW;
        const float a  = angles[(k * NW + w) * 3 + 0];
        const float bb = angles[(k * NW + w) * 3 + 1];
        const float c  = angles[(k * NW + w) * 3 + 2];
        float sa, ca, sb, cb, sc, cc;
        sincosf(a * 0.5f, &sa, &ca);
        sincosf(bb * 0.5f, &sb, &cb);
        sincosf(c * 0.5f, &sc, &cc);
        float2 m00 = make_float2(cb * ca,  sb * sa);
        float2 m01 = make_float2(-sb * ca, -cb * sa);
        float2 m10 = make_float2(sb * ca,  -cb * sa);
        float2 m11 = make_float2(cb * ca,  -sb * sa);
        const float2 e0 = make_float2(cc, -sc), e1 = make_float2(cc, sc);
        const float2 u00 = cmulf(e0, m00), u01 = cmulf(e0, m01);
        const float2 u10 = cmulf(e1, m10), u11 = cmulf(e1, m11);
        const int gi = (k * NW + w) * 4;
        G[gi + 0] = u00; G[gi + 1] = u01; G[gi + 2] = u10; G[gi + 3] = u11;
        if (k == 0) {   // layer-0 STATIC gate (per-sample RY_enc folded in main kernel)
            u0_g[w * 4 + 0] = u00; u0_g[w * 4 + 1] = u01;
            u0_g[w * 4 + 2] = u10; u0_g[w * 4 + 3] = u11;
        }
    }
    __syncthreads();

    // W tables: TR[a'][a] = Re W[a'][a], TI = Im (16x16 per pass), layers 1..3
    {
        const int p = tid >> 6, l6 = tid & 63;
        const int ap = l6 & 15, ahalf = (l6 >> 4) & 1, dup = l6 >> 5;
        const int layer = (p >> 2) + 1, g = p & 3;

        float2 p3;
        if (g == 3) {
            p3 = make_float2((((ap >> 3) & 1) == ahalf) ? 1.f : 0.f, 0.f);
        } else {
            const int wire = 13 - (10 - 4 * g + 3);
            p3 = G[(layer * NW + wire) * 4 + ((ap >> 3) & 1) * 2 + ahalf];
        }
        float2 e0a, e0b, e1a, e1b, e2a, e2b;
        {
            const int r0 = ap & 1, r1 = (ap >> 1) & 1, r2 = (ap >> 2) & 1;
            if (g == 3) {
                const float2* G13 = G + (layer * NW + 13) * 4;
                const float2* G12 = G + (layer * NW + 12) * 4;
                e0a = G13[r0 * 2 + 0]; e0b = G13[r0 * 2 + 1];
                e1a = G12[r1 * 2 + 0]; e1b = G12[r1 * 2 + 1];
                e2a = make_float2(r2 == 0 ? 1.f : 0.f, 0.f);
                e2b = make_float2(r2 == 1 ? 1.f : 0.f, 0.f);
            } else {
                const float2* G0 = G + (layer * NW + (13 - (10 - 4 * g + 0))) * 4;
                const float2* G1 = G + (layer * NW + (13 - (10 - 4 * g + 1))) * 4;
                const float2* G2 = G + (layer * NW + (13 - (10 - 4 * g + 2))) * 4;
                e0a = G0[r0 * 2 + 0]; e0b = G0[r0 * 2 + 1];
                e1a = G1[r1 * 2 + 0]; e1b = G1[r1 * 2 + 1];
                e2a = G2[r2 * 2 + 0]; e2b = G2[r2 * 2 + 1];
            }
        }
        f16x8 frag;
        #pragma unroll
        for (int j2 = 0; j2 < 8; ++j2) {
            float2 v = cmulf(p3, (j2 & 4) ? e2b : e2a);
            v = cmulf(v, (j2 & 2) ? e1b : e1a);
            v = cmulf(v, (j2 & 1) ? e0b : e0a);
            frag[j2] = (f16)(dup ? v.y : v.x);
        }
        *(f16x8*)(wt_g + p * WTP + dup * 256 + wtofs(ap, ahalf)) = frag;
    }
}

// ---------------- main kernel: per-sample ----------------
__global__ __launch_bounds__(THREADS, 4)
void vqc_kernel(const float* __restrict__ x_raw, const f16* __restrict__ wt_g,
                const float2* __restrict__ u0_g, float* __restrict__ out, Plan pl)
{
    extern __shared__ char smem[];
    f16*    Sh  = (f16*)smem;                    // Re [0,16K), Im [16K,32K) f16 (64 KB)
    f16*    Wt  = Sh + 2 * NST;                  // 12 KB shared W tables
    float2* G0c = (float2*)(Wt + NPASS * WTP);   // 14 x {col0_row0, col0_row1}
    float*  red = (float*)(G0c + 2 * NW);

    const int b   = blockIdx.x;
    const int tid = threadIdx.x;
    const int lane = tid & 63, wv = tid >> 6;
    const int q = lane >> 4, m = lane & 15;

    // ---- stage shared W tables: global -> LDS (768 x 16 B, coalesced) ----
    {
        const uint4* src = (const uint4*)wt_g;
        uint4* dst = (uint4*)Wt;
        dst[tid] = src[tid];
        if (tid < 256) dst[512 + tid] = src[512 + tid];
    }
    // ---- per-sample layer-0 encode: col0 of U_static * RY_enc(x_w) ----
    if (tid < NW) {
        const float xe = tanhf(x_raw[b * NW + tid]) * 3.14159265358979f;
        float se, ce;
        sincosf(xe * 0.5f, &se, &ce);
        const float2 u00 = u0_g[tid * 4 + 0], u01 = u0_g[tid * 4 + 1];
        const float2 u10 = u0_g[tid * 4 + 2], u11 = u0_g[tid * 4 + 3];
        G0c[tid * 2 + 0] = make_float2(u00.x * ce + u01.x * se, u00.y * ce + u01.y * se);
        G0c[tid * 2 + 1] = make_float2(u10.x * ce + u11.x * se, u10.y * ce + u11.y * se);
    }
    __syncthreads();

    // ---- init: product state after all layer-0 1q gates, placed via initM ----
    {
        float2 common = make_float2(1.f, 0.f);
        #pragma unroll
        for (int bit = 0; bit < 9; ++bit) {          // x bits 0..8 from tid (wires 13..5)
            const int w = 13 - bit;
            const float2 f = ((tid >> bit) & 1) ? G0c[w * 2 + 1] : G0c[w * 2 + 0];
            common = cmulf(common, f);
        }
        unsigned p9 = 0;
        #pragma unroll
        for (int bit = 0; bit < 9; ++bit)
            p9 ^= ((tid >> bit) & 1) ? (unsigned)pl.initM[bit] : 0u;
        float2 f0[2], f1[2], f2[2], f3[2], f4[2];    // j bits 0..4 -> wires 4,3,2,1,0
        f0[0] = G0c[4*2+0]; f0[1] = G0c[4*2+1];
        f1[0] = G0c[3*2+0]; f1[1] = G0c[3*2+1];
        f2[0] = G0c[2*2+0]; f2[1] = G0c[2*2+1];
        f3[0] = G0c[1*2+0]; f3[1] = G0c[1*2+1];
        f4[0] = G0c[0*2+0]; f4[1] = G0c[0*2+1];
        #pragma unroll
        for (int j = 0; j < 32; ++j) {
            float2 o = cmulf(cmulf(f0[j & 1], f1[(j >> 1) & 1]),
                             cmulf(f2[(j >> 2) & 1], f3[(j >> 3) & 1]));
            o = cmulf(o, f4[(j >> 4) & 1]);
            const float2 amp = cmulf(common, o);
            const unsigned ph = p9
                ^ ((j & 1) ? pl.initM[9]  : 0) ^ ((j & 2)  ? pl.initM[10] : 0)
                ^ ((j & 4) ? pl.initM[11] : 0) ^ ((j & 8)  ? pl.initM[12] : 0)
                ^ ((j & 16) ? pl.initM[13] : 0);
            Sh[ph]       = (f16)amp.x;
            Sh[ph + NST] = (f16)amp.y;
        }
    }
    __syncthreads();

    // ---- 12 MFMA passes, in-place: read 8 tiles -> barrier -> MFMA+write -> barrier ----
    const unsigned plane_off = (unsigned)(q >> 1) << 14;
    const unsigned q01 = (unsigned)(q & 1);
    const f32x4 z4 = {0.f, 0.f, 0.f, 0.f};
    #pragma unroll
    for (int p = 0; p < NPASS; ++p) {
        const PassArg& P = pl.ps[p];
        const unsigned pm = ((m & 1) ? P.Mm[0] : 0) ^ ((m & 2) ? P.Mm[1] : 0)
                          ^ ((m & 4) ? P.Mm[2] : 0) ^ ((m & 8) ? P.Mm[3] : 0);
        const unsigned wb = ((wv & 1) ? P.Mw[0] : 0) ^ ((wv & 2) ? P.Mw[1] : 0)
                          ^ ((wv & 4) ? P.Mw[2] : 0);
        const unsigned b0 = pm ^ wb;
        const f16x8 tr = *(const f16x8*)(Wt + p * WTP +       wtofs((unsigned)m, q01));
        const f16x8 ti = *(const f16x8*)(Wt + p * WTP + 256 + wtofs((unsigned)m, q01));
        const f16x8 bf1 = (q < 2) ? tr : -ti;   // [Wr' ; -Wi']
        const f16x8 bf2 = (q < 2) ? ti : tr;    // [Wi' ;  Wr']
        unsigned sw[8];
        f16x8 av[8];
        #pragma unroll
        for (int tt = 0; tt < 8; ++tt) {
            sw[tt] = b0 ^ ((tt & 1) ? P.Mt[0] : 0)
                        ^ ((tt & 2) ? P.Mt[1] : 0)
                        ^ ((tt & 4) ? P.Mt[2] : 0);
            av[tt] = *(const f16x8*)(Sh + plane_off + (sw[tt] ^ (q01 << 3)));
        }
        __syncthreads();    // all reads complete before any in-place write
        #pragma unroll
        for (int tt = 0; tt < 8; ++tt) {
            const f32x4 d1 = __builtin_amdgcn_mfma_f32_16x16x32_f16(av[tt], bf1, z4, 0, 0, 0);
            const f32x4 d2 = __builtin_amdgcn_mfma_f32_16x16x32_f16(av[tt], bf2, z4, 0, 0, 0);
            union { f16 h[4]; uint2 u; } c1, c2;
            #pragma unroll
            for (int r = 0; r < 4; ++r) { c1.h[r] = (f16)d1[r]; c2.h[r] = (f16)d2[r]; }
            const unsigned wu = sw[tt] ^ ((unsigned)q << 2);
            *(uint2*)(Sh + wu)       = c1.u;   // Re plane, b64
            *(uint2*)(Sh + NST + wu) = c2.u;   // Im plane, b64
        }
        __syncthreads();
    }

    // ---- <Z_0>: sign = parity(s_pre & measR); measR pre-folded by swzu^T ----
    float acc = 0.f;
    {
        const unsigned base = (unsigned)tid * 32;
        const int pb = __popc(base & (unsigned)pl.measR) & 1;
        #pragma unroll
        for (int cch = 0; cch < 4; ++cch) {
            const unsigned co = (unsigned)cch * 8;
            const f16x8 rr = *(const f16x8*)(Sh + (base ^ co));
            const f16x8 ii = *(const f16x8*)(Sh + NST + (base ^ co));
            #pragma unroll
            for (int e = 0; e < 8; ++e) {
                const float re = (float)rr[e], im = (float)ii[e];
                const float pw = fmaf(re, re, im * im);
                const int sgn = pb ^ (__popc((co | (unsigned)e) & (unsigned)pl.measR) & 1);
                acc += sgn ? -pw : pw;
            }
        }
    }
    #pragma unroll
    for (int off = 32; off > 0; off >>= 1) acc += __shfl_down(acc, off);
    if ((tid & 63) == 0) red[wv] = acc;
    __syncthreads();
    if (tid == 0) {
        float s = 0.f;
        #pragma unroll
        for (int i = 0; i < THREADS / 64; ++i) s += red[i];
        out[b] = s;
    }
}

// ---------------- host-side GF(2) layout scheduling ----------------
struct GFm { u16 col[14]; };   // col[b] = image of e_b

static unsigned ringp_host(unsigned x) {
    unsigned s = x;
    s ^= s >> 1; s ^= s >> 2; s ^= s >> 4; s ^= s >> 8;
    s &= 0x3FFFu;
    return (s ^ ((s & 1u) << 13)) & 0x3FFFu;
}
static u16 gf_apply(const GFm& m, u16 v) {
    u16 r = 0;
    for (int b = 0; b < 14; ++b) if ((v >> b) & 1) r ^= m.col[b];
    return r;
}
static GFm gf_compose(const GFm& A, const GFm& B) {
    GFm C;
    for (int b = 0; b < 14; ++b) C.col[b] = gf_apply(A, B.col[b]);
    return C;
}
static void rows_from(const GFm& A, u16 r[14]) {
    for (int i = 0; i < 14; ++i) {
        u16 mm = 0;
        for (int b = 0; b < 14; ++b) mm |= (u16)(((A.col[b] >> i) & 1) << b);
        r[i] = mm;
    }
}
static GFm from_rows(const u16 r[14]) {
    GFm A;
    for (int b = 0; b < 14; ++b) {
        u16 c = 0;
        for (int i = 0; i < 14; ++i) c |= (u16)(((r[i] >> b) & 1) << i);
        A.col[b] = c;
    }
    return A;
}
static GFm gf_inv(const GFm& A) {
    u16 M[14], I[14];
    rows_from(A, M);
    for (int i = 0; i < 14; ++i) I[i] = (u16)(1u << i);
    for (int c = 0; c < 14; ++c) {
        int p = c;
        while (p < 14 && !((M[p] >> c) & 1)) ++p;
        if (p == 14) continue;
        u16 t = M[c]; M[c] = M[p]; M[p] = t;
        t = I[c]; I[c] = I[p]; I[p] = t;
        for (int r2 = 0; r2 < 14; ++r2)
            if (r2 != c && ((M[r2] >> c) & 1)) { M[r2] ^= M[c]; I[r2] ^= I[c]; }
    }
    return from_rows(I);
}

static void build_plan(Plan& pl) {
    GFm ring, ringInv;
    for (int b = 0; b < 14; ++b) ring.col[b] = (u16)ringp_host(1u << b);
    ringInv = gf_inv(ring);

    GFm phi;
    for (int j = 0; j < 4; ++j) phi.col[10 + j] = (u16)(1u << j);
    for (int j = 0; j < 4; ++j) phi.col[6 + j]  = (u16)(1u << (4 + j));
    for (int j = 0; j < 4; ++j) phi.col[2 + j]  = (u16)(1u << (8 + j));
    phi.col[0] = (u16)(1u << 12);
    phi.col[1] = (u16)(1u << 13);

    for (int b = 0; b < 14; ++b) pl.initM[b] = gf_apply(phi, ring.col[b]);

    const int gb[4][4] = {{10,11,12,13},{6,7,8,9},{2,3,4,5},{0,1,6,7}};

    for (int p = 0; p < NPASS; ++p) {
        const int g = p & 3;
        u16 uv[4];
        if (g < 3) for (int j = 0; j < 4; ++j) uv[j] = (u16)(1u << gb[g + 1][j]);
        else       for (int j = 0; j < 4; ++j) uv[j] = ringInv.col[10 + j];
        for (int j = 0; j < 4; ++j) pl.ps[p].Mm[j] = gf_apply(phi, uv[j]);

        u16 span[14]; int ns = 0;
        u16 tv[6]; int nt = 0;
        auto tryAdd = [&](u16 v) -> bool {
            bool ch = true;
            while (ch) {
                ch = false;
                for (int i = 0; i < ns; ++i) {
                    const int tb = 31 - __builtin_clz((unsigned)span[i]);
                    if ((v >> tb) & 1) { v ^= span[i]; ch = true; }
                }
            }
            if (!v) return false;
            span[ns++] = v;
            return true;
        };
        for (int j = 0; j < 4; ++j) tryAdd((u16)(1u << gb[g][j]));
        for (int j = 0; j < 4; ++j) tryAdd(uv[j]);
        for (int b2 = 0; b2 < 14 && nt < 6; ++b2)
            if (tryAdd((u16)(1u << b2))) tv[nt++] = (u16)(1u << b2);
        for (int i = 0; i < 3; ++i) pl.ps[p].Mt[i] = gf_apply(phi, tv[i]);      // tile
        for (int i = 0; i < 3; ++i) pl.ps[p].Mw[i] = gf_apply(phi, tv[i + 3]);  // wave

        GFm Bm;
        for (int j = 0; j < 4; ++j) Bm.col[j]     = (u16)(1u << gb[g][j]);
        for (int j = 0; j < 4; ++j) Bm.col[4 + j] = uv[j];
        for (int i = 0; i < 6; ++i) Bm.col[8 + i] = tv[i];
        GFm Binv = gf_inv(Bm);
        u16 img[14];
        for (int j = 0; j < 4; ++j) img[j]     = pl.ps[p].Mm[j];
        for (int j = 0; j < 4; ++j) img[4 + j] = (u16)(1u << j);
        for (int i = 0; i < 6; ++i) img[8 + i] = gf_apply(phi, tv[i]);
        GFm nphi;
        for (int b2 = 0; b2 < 14; ++b2) {
            const u16 coef = gf_apply(Binv, (u16)(1u << b2));
            u16 v = 0;
            for (int j = 0; j < 14; ++j) if ((coef >> j) & 1) v ^= img[j];
            nphi.col[b2] = v;
        }
        if (g == 3) nphi = gf_compose(nphi, ringInv);
        phi = nphi;
    }

    GFm pinv = gf_inv(phi);
    u16 rows[14];
    rows_from(pinv, rows);
    pl.measR = rows[13];
    pl._pad = 0;
}

// ---- fold the device bank-spread hash swzu into all masks (GF(2)-linear,
// involution): out[3]=s3^s6^s9^s11, out[4]=s4^s7^s10^s12, out[5]=s5^s8^s11^s13 ----
static u16 swz_h(u16 v) {
    return (u16)(v ^ ((((v >> 6) ^ (v >> 9) ^ (v >> 11)) & 7u) << 3));
}
static u16 swzT_h(u16 r) {      // transpose, for parity masks
    u16 o = r;
    if ((r >> 3) & 1) o ^= (u16)((1u << 6) | (1u << 9)  | (1u << 11));
    if ((r >> 4) & 1) o ^= (u16)((1u << 7) | (1u << 10) | (1u << 12));
    if ((r >> 5) & 1) o ^= (u16)((1u << 8) | (1u << 11) | (1u << 13));
    return o;
}
static void fold_swzu(Plan& pl) {
    for (int p = 0; p < NPASS; ++p) {
        for (int j = 0; j < 4; ++j) pl.ps[p].Mm[j] = swz_h(pl.ps[p].Mm[j]);
        for (int j = 0; j < 3; ++j) pl.ps[p].Mt[j] = swz_h(pl.ps[p].Mt[j]);
        for (int j = 0; j < 3; ++j) pl.ps[p].Mw[j] = swz_h(pl.ps[p].Mw[j]);
    }
    for (int b = 0; b < 14; ++b) pl.initM[b] = swz_h(pl.initM[b]);
    pl.measR = swzT_h(pl.measR);
}

extern "C" void kernel_launch(void* const* d_in, const int* in_sizes, int n_in,
                              void* d_out, int out_size, void* d_ws, size_t ws_size,
                              hipStream_t stream) {
    const float* x_raw  = (const float*)d_in[0];
    const float* angles = (const float*)d_in[1];
    float* out = (float*)d_out;
    const int bsz = in_sizes[0] / NW;

    Plan pl;
    build_plan(pl);
    fold_swzu(pl);

    // d_ws layout: [0,12288) W tables (f16), [12288,12736) layer-0 static gates
    f16*    wt_g = (f16*)d_ws;
    float2* u0_g = (float2*)((char*)d_ws + (size_t)NPASS * WTP * sizeof(f16));

    vqc_pre<<<dim3(1), dim3(PRETHR), 0, stream>>>(angles, wt_g, u0_g);

    // 64K state + 12K W tables + 240B G0col/red ~= 78.1 KB -> 2 blocks/CU
    const size_t lds = (size_t)2 * NST * sizeof(f16)
                     + (size_t)NPASS * WTP * sizeof(f16)
                     + (size_t)(2 * NW) * sizeof(float2)
                     + (size_t)(THREADS / 64) * sizeof(float);
    (void)hipFuncSetAttribute((const void*)vqc_kernel,
                              hipFuncAttributeMaxDynamicSharedMemorySize, (int)lds);
    vqc_kernel<<<dim3(bsz), dim3(THREADS), lds, stream>>>(x_raw, wt_g, u0_g, out, pl);
}